// Round 19
// baseline (117.281 us; speedup 1.0000x reference)
//
#include <hip/hip_runtime.h>
#include <hip/hip_bf16.h>
#include <math.h>

#define BB 64
#define SS 400
#define F2H 512
#define HID 256
#define EMB 128
#define NGATE 1024
#define VOC 50000
#define CH 64
#define NCHK 7
#define NKC 16
#define OWF (VOC * HID)   // 12,800,000 floats in out_W

typedef short bf16x8 __attribute__((ext_vector_type(8)));
typedef float f32x4 __attribute__((ext_vector_type(4)));

__device__ __forceinline__ float sigm(float x) { return 1.0f / (1.0f + __expf(-x)); }

__device__ __forceinline__ float ftanh(float x) {
    float e = __expf(2.0f * x);
    return 1.0f - 2.0f / (e + 1.0f);
}

__device__ __forceinline__ ushort f2bf(float x) {
    uint32_t u = __float_as_uint(x);
    uint32_t r = u + 0x7FFFu + ((u >> 16) & 1u);
    return (ushort)(r >> 16);
}

__device__ __forceinline__ float bf2f(ushort u) {
    return __uint_as_float(((uint32_t)u) << 16);
}

__device__ __forceinline__ bf16x8 cvt8(float4 a, float4 b) {
    __hip_bfloat162 p0 = __float22bfloat162_rn({a.x, a.y});
    __hip_bfloat162 p1 = __float22bfloat162_rn({a.z, a.w});
    __hip_bfloat162 p2 = __float22bfloat162_rn({b.x, b.y});
    __hip_bfloat162 p3 = __float22bfloat162_rn({b.z, b.w});
    union { bf16x8 v; uint32_t u[4]; } r;
    r.u[0] = *(uint32_t*)&p0;
    r.u[1] = *(uint32_t*)&p1;
    r.u[2] = *(uint32_t*)&p2;
    r.u[3] = *(uint32_t*)&p3;
    return r.v;
}

// ---------------- K1: fused head — gates(K=384 direct) + LSTM pointwise + hproj + wenc pack ----------------
// grid 80: blocks 0..63 per-batch head; blocks 64..79 wenc fragment packing
__global__ __launch_bounds__(256) void k_head(
    const int* __restrict__ word, const float* __restrict__ hidden,
    const float* __restrict__ cell, const float* __restrict__ embed,
    const float* __restrict__ W_ih, const float* __restrict__ W_hh,
    const float* __restrict__ b_ih, const float* __restrict__ b_hh,
    const float* __restrict__ attn_W, const float* __restrict__ attn_b,
    float* __restrict__ h_out, float* __restrict__ c_out, float* __restrict__ hproj,
    ushort* __restrict__ wenc_pk)
{
    const int blk = blockIdx.x;
    const int tid = threadIdx.x;

    if (blk >= 64) {   // wenc fragment-packed prep (16 blocks)
        int gt = blk - 64;
#pragma unroll
        for (int r = 0; r < 4; ++r) {
            int u = gt * 1024 + r * 256 + tid;
            int l = u & 63;
            int t = (u >> 6) & 15;
            int nt = u >> 10;
            int n = nt * 16 + (l & 15);
            int k0 = t * 32 + (l >> 4) * 8;
            const float4* src = (const float4*)&attn_W[n * 768 + k0];
            float4 f0 = src[0], f1 = src[1];
            *(bf16x8*)&wenc_pk[(size_t)u * 8] = cvt8(f0, f1);
        }
        return;
    }

    const int b = blk;
    __shared__ float Arow[384];
    __shared__ float hrow[HID];

    if (tid < 128) Arow[tid] = embed[(size_t)word[b] * EMB + tid];
    Arow[128 + tid] = hidden[b * HID + tid];
    __syncthreads();

    // 4 gates per thread: g = j*256 + tid  (i,f,g,o)
    float g4[4];
#pragma unroll
    for (int j = 0; j < 4; ++j) {
        int g = j * 256 + tid;
        float acc = b_ih[g] + b_hh[g];
        const float* wi = W_ih + (size_t)g * EMB;
#pragma unroll 8
        for (int k = 0; k < EMB; k += 4) {
            float4 wv = *(const float4*)&wi[k];
            acc += Arow[k] * wv.x + Arow[k + 1] * wv.y + Arow[k + 2] * wv.z + Arow[k + 3] * wv.w;
        }
        const float* wh = W_hh + (size_t)g * HID;
#pragma unroll 8
        for (int k = 0; k < HID; k += 4) {
            float4 wv = *(const float4*)&wh[k];
            acc += Arow[128 + k] * wv.x + Arow[129 + k] * wv.y + Arow[130 + k] * wv.z + Arow[131 + k] * wv.w;
        }
        g4[j] = acc;
    }

    float c = sigm(g4[1]) * cell[b * HID + tid] + sigm(g4[0]) * tanhf(g4[2]);
    float h = tanhf(sigm(g4[3]) * tanhf(c));
    c_out[b * HID + tid] = c;
    h_out[b * HID + tid] = h;
    hrow[tid] = h;
    __syncthreads();

    float acc = attn_b[tid];
    const float* wr = attn_W + tid * 768 + 512;
#pragma unroll 8
    for (int k = 0; k < HID; k += 4) {
        float4 wv = *(const float4*)&wr[k];
        acc += hrow[k] * wv.x + hrow[k + 1] * wv.y + hrow[k + 2] * wv.z + hrow[k + 3] * wv.w;
    }
    hproj[b * HID + tid] = acc;
}

// ---------------- K2: fused attention + out_W L3-prefetch tail ----------------
// grid = 64 b x 7 chunks of 64 s; 512 threads = 8 waves (wave: 32 rows x 64 cols)
__global__ __launch_bounds__(512, 4) void k_attn(
    const float* __restrict__ enc, const ushort* __restrict__ wenc_pk,
    const float* __restrict__ hproj, const float* __restrict__ vvec,
    float* __restrict__ ctxp, float* __restrict__ mls,
    const float* __restrict__ out_W, float* __restrict__ pfdump)
{
    const int b   = blockIdx.x / NCHK;
    const int chk = blockIdx.x % NCHK;
    const int s0  = chk * CH;
    const int tid = threadIdx.x;
    const int l = tid & 63;
    const int w = tid >> 6;
    const int wr = w >> 2, wc = w & 3;
    const int brow0 = b * SS;
    const int ln = l & 15, q = l >> 4;

    __shared__ ushort Asm[CH * 512];
    __shared__ float ps[CH];
    __shared__ float pool[7 * 64 * 8];
    float (*epart)[4] = (float(*)[4])pool;
    float* scratch = pool;

#pragma unroll
    for (int i = 0; i < 8; ++i) {
        int u = i * 512 + tid;
        int row = u >> 6, c16 = u & 63;
        int sr = s0 + row;
        if (sr >= SS) sr = SS - 1;
        const float4* src = (const float4*)&enc[(size_t)(brow0 + sr) * F2H + c16 * 8];
        float4 f0 = src[0], f1 = src[1];
        *(bf16x8*)&Asm[row * 512 + ((c16 ^ (row & 7)) * 8)] = cvt8(f0, f1);
    }
    __syncthreads();

    f32x4 acc[2][4];
#pragma unroll
    for (int mf = 0; mf < 2; ++mf)
#pragma unroll
        for (int nf = 0; nf < 4; ++nf) acc[mf][nf] = (f32x4){0.f, 0.f, 0.f, 0.f};

    const ushort* bbase = wenc_pk + ((size_t)(wc * 4) * 1024 + l) * 8;

#pragma unroll
    for (int t = 0; t < NKC; ++t) {
        bf16x8 af[2], bfr[4];
#pragma unroll
        for (int nf = 0; nf < 4; ++nf)
            bfr[nf] = *(const bf16x8*)(bbase + ((size_t)nf * 1024 + t * 64) * 8);
#pragma unroll
        for (int mf = 0; mf < 2; ++mf) {
            int row = wr * 32 + mf * 16 + ln;
            int c16 = (t * 4 + q) ^ (row & 7);
            af[mf] = *(const bf16x8*)&Asm[row * 512 + c16 * 8];
        }
#pragma unroll
        for (int mf = 0; mf < 2; ++mf)
#pragma unroll
            for (int nf = 0; nf < 4; ++nf)
                acc[mf][nf] = __builtin_amdgcn_mfma_f32_16x16x32_bf16(
                    af[mf], bfr[nf], acc[mf][nf], 0, 0, 0);
    }

    float vv[4];
#pragma unroll
    for (int nf = 0; nf < 4; ++nf) vv[nf] = vvec[wc * 64 + nf * 16 + ln];
    const float* hp = hproj + b * HID;

#pragma unroll
    for (int mf = 0; mf < 2; ++mf) {
#pragma unroll
        for (int r = 0; r < 4; ++r) {
            int row = wr * 32 + mf * 16 + q * 4 + r;
            float p = 0.0f;
#pragma unroll
            for (int nf = 0; nf < 4; ++nf) {
                int col = wc * 64 + nf * 16 + ln;
                p += vv[nf] * ftanh(acc[mf][nf][r] + hp[col]);
            }
#pragma unroll
            for (int off = 8; off >= 1; off >>= 1) p += __shfl_xor(p, off);
            if (ln == 0) epart[row][wc] = p;
        }
    }
    __syncthreads();

    if (tid < 64) {
        int s = s0 + tid;
        float es = (s < SS)
            ? ((epart[tid][0] + epart[tid][1]) + (epart[tid][2] + epart[tid][3]))
            : -1e30f;
        float m = es;
#pragma unroll
        for (int off = 32; off >= 1; off >>= 1) m = fmaxf(m, __shfl_xor(m, off));
        float p = __expf(es - m);
        ps[tid] = p;
        float sum = p;
#pragma unroll
        for (int off = 32; off >= 1; off >>= 1) sum += __shfl_xor(sum, off);
        if (tid == 0) {
            mls[(b * NCHK + chk) * 2 + 0] = m;
            mls[(b * NCHK + chk) * 2 + 1] = sum;
        }
    }
    __syncthreads();

    {
        const int c16 = l;
        float ca[8];
#pragma unroll
        for (int j = 0; j < 8; ++j) ca[j] = 0.f;
#pragma unroll
        for (int r = 0; r < 8; ++r) {
            int row = w * 8 + r;
            float p = ps[row];
            bf16x8 v = *(const bf16x8*)&Asm[row * 512 + ((c16 ^ (row & 7)) * 8)];
#pragma unroll
            for (int j = 0; j < 8; ++j) ca[j] += p * bf2f((ushort)v[j]);
        }
        if (w != 0) {
#pragma unroll
            for (int j = 0; j < 8; ++j) scratch[((w - 1) * 64 + c16) * 8 + j] = ca[j];
        }
        __syncthreads();
        if (w == 0) {
#pragma unroll
            for (int g = 0; g < 7; ++g)
#pragma unroll
                for (int j = 0; j < 8; ++j) ca[j] += scratch[(g * 64 + c16) * 8 + j];
            float4 o0 = {ca[0], ca[1], ca[2], ca[3]};
            float4 o1 = {ca[4], ca[5], ca[6], ca[7]};
            float* dst = ctxp + (size_t)(b * NCHK + chk) * F2H + c16 * 8;
            *(float4*)dst = o0;
            *(float4*)(dst + 4) = o1;
        }
    }

    // L3-prefetch tail: stream this block's contiguous slice of out_W (keep-alive sum)
    {
        const int pb = blockIdx.x;              // 0..447
        size_t base = (size_t)pb * 28672;       // 448*28672 >= 12.8M
        float s = 0.f;
#pragma unroll
        for (int i = 0; i < 14; ++i) {
            size_t idx = base + (size_t)i * 2048 + (size_t)tid * 4;
            if (idx > (size_t)(OWF - 4)) idx = OWF - 4;
            float4 v = *(const float4*)&out_W[idx];
            s += v.x + v.y + v.z + v.w;
        }
        pfdump[pb * 512 + tid] = s;
    }
}

// ---------------- K3: weighted combine over 7 chunks + concat + projection -> bf16 catp ----------------
__global__ __launch_bounds__(256) void k_comb(
    const float* __restrict__ ctxp, const float* __restrict__ mls,
    const float* __restrict__ hvals, const float* __restrict__ proj_W,
    const float* __restrict__ proj_b, ushort* __restrict__ catp_bf)
{
    const int b = blockIdx.x;
    const int j = threadIdx.x;
    __shared__ float cat[768];

    float m[NCHK], lv[NCHK];
#pragma unroll
    for (int c = 0; c < NCHK; ++c) {
        m[c]  = mls[(b * NCHK + c) * 2 + 0];
        lv[c] = mls[(b * NCHK + c) * 2 + 1];
    }
    float ms = m[0];
#pragma unroll
    for (int c = 1; c < NCHK; ++c) ms = fmaxf(ms, m[c]);
    float wgt[NCHK], L = 0.f;
#pragma unroll
    for (int c = 0; c < NCHK; ++c) { wgt[c] = __expf(m[c] - ms); L += lv[c] * wgt[c]; }
    float inv = 1.0f / L;

#pragma unroll
    for (int p = 0; p < 2; ++p) {
        int f = j + p * 256;
        float s = 0.f;
#pragma unroll
        for (int c = 0; c < NCHK; ++c) s += ctxp[((size_t)(b * NCHK + c)) * F2H + f] * wgt[c];
        cat[f] = s * inv;
    }
    cat[F2H + j] = hvals[b * HID + j];
    __syncthreads();

    float acc = proj_b[j];
    const float* wr = proj_W + j * 768;
#pragma unroll 8
    for (int k = 0; k < 768; k += 4) {
        float4 wv = *(const float4*)&wr[k];
        acc += cat[k] * wv.x + cat[k + 1] * wv.y + cat[k + 2] * wv.z + cat[k + 3] * wv.w;
    }
    catp_bf[b * HID + j] = f2bf(acc);
}

// ---------------- K4: output GEMM — wave-contiguous out_W staging (L3-hot) ----------------
__global__ __launch_bounds__(512, 4) void k_out(
    const ushort* __restrict__ catp_bf, const float* __restrict__ out_W,
    const float* __restrict__ out_b, float* __restrict__ wd)
{
    __shared__ ushort Cs[64 * 256];
    __shared__ ushort Ws[64 * 256];

    const int tid = threadIdx.x;
    const int l = tid & 63;
    const int w = tid >> 6;
    const int q = l >> 4;
    const int ln = l & 15;
    const int wr = w >> 2, wc = w & 3;
    const int v0 = blockIdx.x * 64;

#pragma unroll
    for (int i = 0; i < 4; ++i) {
        int u = i * 512 + tid;
        int n = u >> 5, c16 = u & 31;
        bf16x8 o = *(const bf16x8*)&catp_bf[n * HID + c16 * 8];
        *(bf16x8*)&Cs[n * 256 + ((c16 ^ (n & 7)) * 8)] = o;
    }
#pragma unroll
    for (int i = 0; i < 4; ++i) {
        int idx = i * 512 + tid;
        int row = idx >> 5, g = idx & 31;
        int vr = v0 + row; if (vr >= VOC) vr = VOC - 1;
        const float4* src = (const float4*)&out_W[(size_t)vr * HID + g * 8];
        float4 f0 = src[0], f1 = src[1];
        *(bf16x8*)&Ws[row * 256 + ((g ^ (row & 7)) * 8)] = cvt8(f0, f1);
    }
    __syncthreads();

    f32x4 acc[2];
    acc[0] = (f32x4){0.f, 0.f, 0.f, 0.f};
    acc[1] = (f32x4){0.f, 0.f, 0.f, 0.f};

    const int vrow = wc * 16 + ln;
#pragma unroll
    for (int s = 0; s < 8; ++s) {
        int gB = (s * 4 + q) ^ (vrow & 7);
        bf16x8 bfr = *(const bf16x8*)&Ws[vrow * 256 + gB * 8];
#pragma unroll
        for (int mf = 0; mf < 2; ++mf) {
            int arow = wr * 32 + mf * 16 + ln;
            int gA = (s * 4 + q) ^ (arow & 7);
            bf16x8 a = *(const bf16x8*)&Cs[arow * 256 + gA * 8];
            acc[mf] = __builtin_amdgcn_mfma_f32_16x16x32_bf16(a, bfr, acc[mf], 0, 0, 0);
        }
    }

    const int v = v0 + vrow;
    if (v < VOC) {
        float bias = out_b[v];
#pragma unroll
        for (int mf = 0; mf < 2; ++mf) {
            int b0 = wr * 32 + mf * 16 + q * 4;
#pragma unroll
            for (int r = 0; r < 4; ++r)
                wd[(size_t)(b0 + r) * VOC + v] = acc[mf][r] + bias;
        }
    }
}

extern "C" void kernel_launch(void* const* d_in, const int* in_sizes, int n_in,
                              void* d_out, int out_size, void* d_ws, size_t ws_size,
                              hipStream_t stream) {
    const int*   word   = (const int*)  d_in[0];
    const float* hidden = (const float*)d_in[1];
    const float* cell   = (const float*)d_in[2];
    const float* enc    = (const float*)d_in[3];
    const float* embed  = (const float*)d_in[5];
    const float* W_ih   = (const float*)d_in[6];
    const float* W_hh   = (const float*)d_in[7];
    const float* b_ih   = (const float*)d_in[8];
    const float* b_hh   = (const float*)d_in[9];
    const float* attn_W = (const float*)d_in[10];
    const float* attn_b = (const float*)d_in[11];
    const float* vvec   = (const float*)d_in[12];
    const float* proj_W = (const float*)d_in[13];
    const float* proj_b = (const float*)d_in[14];
    const float* out_W  = (const float*)d_in[15];
    const float* out_b  = (const float*)d_in[16];

    float* wd  = (float*)d_out;
    float* h_o = wd + (size_t)BB * VOC;
    float* c_o = h_o + BB * HID;

    float* ws    = (float*)d_ws;
    float* hproj = ws;                          // 16384
    float* ctxp  = hproj + 16384;               // 64*7*512 = 229376
    float* mls   = ctxp + 229376;               // 896
    ushort* wenc_pk = (ushort*)(mls + 896);     // 131072 ushorts
    ushort* catp_bf = wenc_pk + 131072;         // 16384 ushorts
    float* pfdump = (float*)(catp_bf + 16384);  // 448*512 = 229376 floats

    k_head<<<80, 256, 0, stream>>>(word, hidden, cell, embed, W_ih, W_hh, b_ih, b_hh,
                                   attn_W, attn_b, h_o, c_o, hproj, wenc_pk);
    k_attn<<<BB * NCHK, 512, 0, stream>>>(enc, wenc_pk, hproj, vvec, ctxp, mls, out_W, pfdump);
    k_comb<<<64, 256, 0, stream>>>(ctxp, mls, h_o, proj_W, proj_b, catp_bf);
    k_out<<<782, 512, 0, stream>>>(catp_bf, out_W, out_b, wd);
}

// Round 20
// 86.559 us; speedup vs baseline: 1.3549x; 1.3549x over previous
//
#include <hip/hip_runtime.h>
#include <hip/hip_bf16.h>
#include <math.h>

#define BB 64
#define SS 400
#define F2H 512
#define HID 256
#define EMB 128
#define NGATE 1024
#define VOC 50000
#define CH 64
#define NCHK 7
#define NKC 16
#define OWF (VOC * HID)

typedef short bf16x8 __attribute__((ext_vector_type(8)));
typedef float f32x4 __attribute__((ext_vector_type(4)));

__device__ __forceinline__ float sigm(float x) { return 1.0f / (1.0f + __expf(-x)); }

__device__ __forceinline__ float ftanh(float x) {
    float e = __expf(2.0f * x);
    return 1.0f - 2.0f / (e + 1.0f);
}

__device__ __forceinline__ ushort f2bf(float x) {
    uint32_t u = __float_as_uint(x);
    uint32_t r = u + 0x7FFFu + ((u >> 16) & 1u);
    return (ushort)(r >> 16);
}

__device__ __forceinline__ float bf2f(ushort u) {
    return __uint_as_float(((uint32_t)u) << 16);
}

__device__ __forceinline__ bf16x8 cvt8(float4 a, float4 b) {
    __hip_bfloat162 p0 = __float22bfloat162_rn({a.x, a.y});
    __hip_bfloat162 p1 = __float22bfloat162_rn({a.z, a.w});
    __hip_bfloat162 p2 = __float22bfloat162_rn({b.x, b.y});
    __hip_bfloat162 p3 = __float22bfloat162_rn({b.z, b.w});
    union { bf16x8 v; uint32_t u[4]; } r;
    r.u[0] = *(uint32_t*)&p0;
    r.u[1] = *(uint32_t*)&p1;
    r.u[2] = *(uint32_t*)&p2;
    r.u[3] = *(uint32_t*)&p3;
    return r.v;
}

// ---------------- K1a: gates partial GEMM + fused wenc MFMA-fragment packing ----------------
__global__ __launch_bounds__(256) void k_gates(
    const int* __restrict__ word, const float* __restrict__ hidden,
    const float* __restrict__ embed, const float* __restrict__ W_ih,
    const float* __restrict__ W_hh, float* __restrict__ part,
    const float* __restrict__ attn_W, ushort* __restrict__ wenc_pk)
{
    const int gt = blockIdx.x;
    const int ks = blockIdx.y;
    const int tid = threadIdx.x;

    if (ks == 4) {   // wenc fragment-packed prep
#pragma unroll
        for (int r = 0; r < 4; ++r) {
            int u = gt * 1024 + r * 256 + tid;
            int l = u & 63;
            int t = (u >> 6) & 15;
            int nt = u >> 10;
            int n = nt * 16 + (l & 15);
            int k0 = t * 32 + (l >> 4) * 8;
            const float4* src = (const float4*)&attn_W[n * 768 + k0];
            float4 f0 = src[0], f1 = src[1];
            *(bf16x8*)&wenc_pk[(size_t)u * 8] = cvt8(f0, f1);
        }
        return;
    }

    __shared__ float As[32 * 68];
    __shared__ float Bs[32 * 68];
    const int g0 = gt * 64;
    const int k0 = ks * 96;
    float acc[4][4];
#pragma unroll
    for (int i = 0; i < 4; ++i)
#pragma unroll
        for (int j = 0; j < 4; ++j) acc[i][j] = 0.0f;

    const int tb = tid >> 4;
    const int tg = tid & 15;
    const int srow = tid >> 3;
    const int skk = (tid & 7) * 4;

    for (int c = 0; c < 3; ++c) {
        const int kc = k0 + c * 32;
#pragma unroll
        for (int p = 0; p < 2; ++p) {
            int rr = srow + p * 32;
            int gk = kc + skk;
            float4 f;
            if (gk < EMB) {
                int w = word[rr];
                f = *(const float4*)&embed[w * EMB + gk];
            } else {
                f = *(const float4*)&hidden[rr * HID + gk - EMB];
            }
            As[(skk + 0) * 68 + rr] = f.x;
            As[(skk + 1) * 68 + rr] = f.y;
            As[(skk + 2) * 68 + rr] = f.z;
            As[(skk + 3) * 68 + rr] = f.w;
        }
#pragma unroll
        for (int p = 0; p < 2; ++p) {
            int nn = srow + p * 32;
            int g = g0 + nn;
            int gk = kc + skk;
            float4 f;
            if (gk < EMB) f = *(const float4*)&W_ih[g * EMB + gk];
            else          f = *(const float4*)&W_hh[g * HID + gk - EMB];
            Bs[(skk + 0) * 68 + nn] = f.x;
            Bs[(skk + 1) * 68 + nn] = f.y;
            Bs[(skk + 2) * 68 + nn] = f.z;
            Bs[(skk + 3) * 68 + nn] = f.w;
        }
        __syncthreads();
#pragma unroll 8
        for (int k = 0; k < 32; ++k) {
            float4 a = *(const float4*)&As[k * 68 + tb * 4];
            float4 b = *(const float4*)&Bs[k * 68 + tg * 4];
            float av[4] = {a.x, a.y, a.z, a.w};
            float bv[4] = {b.x, b.y, b.z, b.w};
#pragma unroll
            for (int i = 0; i < 4; ++i)
#pragma unroll
                for (int j = 0; j < 4; ++j) acc[i][j] += av[i] * bv[j];
        }
        __syncthreads();
    }
    float* dst = part + ks * (BB * NGATE);
#pragma unroll
    for (int i = 0; i < 4; ++i) {
        int b = tb * 4 + i;
        float4 o = {acc[i][0], acc[i][1], acc[i][2], acc[i][3]};
        *(float4*)&dst[b * NGATE + g0 + tg * 4] = o;
    }
}

// ---------------- K1b: LSTM pointwise + hproj ----------------
__global__ __launch_bounds__(256) void k_lstm(
    const float* __restrict__ part, const float* __restrict__ cell,
    const float* __restrict__ b_ih, const float* __restrict__ b_hh,
    const float* __restrict__ attn_W, const float* __restrict__ attn_b,
    float* __restrict__ h_out, float* __restrict__ c_out, float* __restrict__ hproj)
{
    const int b = blockIdx.x;
    const int u = threadIdx.x;
    __shared__ float hrow[HID];

    float gi = b_ih[u] + b_hh[u];
    float gf = b_ih[u + 256] + b_hh[u + 256];
    float gg = b_ih[u + 512] + b_hh[u + 512];
    float go = b_ih[u + 768] + b_hh[u + 768];
#pragma unroll
    for (int ks = 0; ks < 4; ++ks) {
        const float* p = part + ks * (BB * NGATE) + b * NGATE;
        gi += p[u];
        gf += p[u + 256];
        gg += p[u + 512];
        go += p[u + 768];
    }
    float c = sigm(gf) * cell[b * HID + u] + sigm(gi) * tanhf(gg);
    float h = tanhf(sigm(go) * tanhf(c));
    c_out[b * HID + u] = c;
    h_out[b * HID + u] = h;
    hrow[u] = h;
    __syncthreads();

    float acc = attn_b[u];
    const float* wr = attn_W + u * 768 + 512;
#pragma unroll 8
    for (int k = 0; k < HID; k += 4) {
        float4 w = *(const float4*)&wr[k];
        acc += hrow[k] * w.x + hrow[k + 1] * w.y + hrow[k + 2] * w.z + hrow[k + 3] * w.w;
    }
    hproj[b * HID + u] = acc;
}

// ---------------- K2: fused attention + out_W L3-prefetch tail ----------------
__global__ __launch_bounds__(512, 4) void k_attn(
    const float* __restrict__ enc, const ushort* __restrict__ wenc_pk,
    const float* __restrict__ hproj, const float* __restrict__ vvec,
    float* __restrict__ ctxp, float* __restrict__ mls,
    const float* __restrict__ out_W, float* __restrict__ pfdump)
{
    const int b   = blockIdx.x / NCHK;
    const int chk = blockIdx.x % NCHK;
    const int s0  = chk * CH;
    const int tid = threadIdx.x;
    const int l = tid & 63;
    const int w = tid >> 6;
    const int wr = w >> 2, wc = w & 3;
    const int brow0 = b * SS;
    const int ln = l & 15, q = l >> 4;

    __shared__ ushort Asm[CH * 512];
    __shared__ float ps[CH];
    __shared__ float pool[7 * 64 * 8];
    float (*epart)[4] = (float(*)[4])pool;
    float* scratch = pool;

#pragma unroll
    for (int i = 0; i < 8; ++i) {
        int u = i * 512 + tid;
        int row = u >> 6, c16 = u & 63;
        int sr = s0 + row;
        if (sr >= SS) sr = SS - 1;
        const float4* src = (const float4*)&enc[(size_t)(brow0 + sr) * F2H + c16 * 8];
        float4 f0 = src[0], f1 = src[1];
        *(bf16x8*)&Asm[row * 512 + ((c16 ^ (row & 7)) * 8)] = cvt8(f0, f1);
    }
    __syncthreads();

    f32x4 acc[2][4];
#pragma unroll
    for (int mf = 0; mf < 2; ++mf)
#pragma unroll
        for (int nf = 0; nf < 4; ++nf) acc[mf][nf] = (f32x4){0.f, 0.f, 0.f, 0.f};

    const ushort* bbase = wenc_pk + ((size_t)(wc * 4) * 1024 + l) * 8;

#pragma unroll
    for (int t = 0; t < NKC; ++t) {
        bf16x8 af[2], bfr[4];
#pragma unroll
        for (int nf = 0; nf < 4; ++nf)
            bfr[nf] = *(const bf16x8*)(bbase + ((size_t)nf * 1024 + t * 64) * 8);
#pragma unroll
        for (int mf = 0; mf < 2; ++mf) {
            int row = wr * 32 + mf * 16 + ln;
            int c16 = (t * 4 + q) ^ (row & 7);
            af[mf] = *(const bf16x8*)&Asm[row * 512 + c16 * 8];
        }
#pragma unroll
        for (int mf = 0; mf < 2; ++mf)
#pragma unroll
            for (int nf = 0; nf < 4; ++nf)
                acc[mf][nf] = __builtin_amdgcn_mfma_f32_16x16x32_bf16(
                    af[mf], bfr[nf], acc[mf][nf], 0, 0, 0);
    }

    float vv[4];
#pragma unroll
    for (int nf = 0; nf < 4; ++nf) vv[nf] = vvec[wc * 64 + nf * 16 + ln];
    const float* hp = hproj + b * HID;

#pragma unroll
    for (int mf = 0; mf < 2; ++mf) {
#pragma unroll
        for (int r = 0; r < 4; ++r) {
            int row = wr * 32 + mf * 16 + q * 4 + r;
            float p = 0.0f;
#pragma unroll
            for (int nf = 0; nf < 4; ++nf) {
                int col = wc * 64 + nf * 16 + ln;
                p += vv[nf] * ftanh(acc[mf][nf][r] + hp[col]);
            }
#pragma unroll
            for (int off = 8; off >= 1; off >>= 1) p += __shfl_xor(p, off);
            if (ln == 0) epart[row][wc] = p;
        }
    }
    __syncthreads();

    if (tid < 64) {
        int s = s0 + tid;
        float es = (s < SS)
            ? ((epart[tid][0] + epart[tid][1]) + (epart[tid][2] + epart[tid][3]))
            : -1e30f;
        float m = es;
#pragma unroll
        for (int off = 32; off >= 1; off >>= 1) m = fmaxf(m, __shfl_xor(m, off));
        float p = __expf(es - m);
        ps[tid] = p;
        float sum = p;
#pragma unroll
        for (int off = 32; off >= 1; off >>= 1) sum += __shfl_xor(sum, off);
        if (tid == 0) {
            mls[(b * NCHK + chk) * 2 + 0] = m;
            mls[(b * NCHK + chk) * 2 + 1] = sum;
        }
    }
    __syncthreads();

    {
        const int c16 = l;
        float ca[8];
#pragma unroll
        for (int j = 0; j < 8; ++j) ca[j] = 0.f;
#pragma unroll
        for (int r = 0; r < 8; ++r) {
            int row = w * 8 + r;
            float p = ps[row];
            bf16x8 v = *(const bf16x8*)&Asm[row * 512 + ((c16 ^ (row & 7)) * 8)];
#pragma unroll
            for (int j = 0; j < 8; ++j) ca[j] += p * bf2f((ushort)v[j]);
        }
        if (w != 0) {
#pragma unroll
            for (int j = 0; j < 8; ++j) scratch[((w - 1) * 64 + c16) * 8 + j] = ca[j];
        }
        __syncthreads();
        if (w == 0) {
#pragma unroll
            for (int g = 0; g < 7; ++g)
#pragma unroll
                for (int j = 0; j < 8; ++j) ca[j] += scratch[(g * 64 + c16) * 8 + j];
            float4 o0 = {ca[0], ca[1], ca[2], ca[3]};
            float4 o1 = {ca[4], ca[5], ca[6], ca[7]};
            float* dst = ctxp + (size_t)(b * NCHK + chk) * F2H + c16 * 8;
            *(float4*)dst = o0;
            *(float4*)(dst + 4) = o1;
        }
    }

    // L3-prefetch tail: stream this block's contiguous slice of out_W (keep-alive sum)
    {
        const int pb = blockIdx.x;
        size_t base = (size_t)pb * 28672;
        float s = 0.f;
#pragma unroll
        for (int i = 0; i < 14; ++i) {
            size_t idx = base + (size_t)i * 2048 + (size_t)tid * 4;
            if (idx > (size_t)(OWF - 4)) idx = OWF - 4;
            float4 v = *(const float4*)&out_W[idx];
            s += v.x + v.y + v.z + v.w;
        }
        pfdump[pb * 512 + tid] = s;
    }
}

// ---------------- K3: weighted combine over 7 chunks + concat + projection -> bf16 catp ----------------
__global__ __launch_bounds__(256) void k_comb(
    const float* __restrict__ ctxp, const float* __restrict__ mls,
    const float* __restrict__ hvals, const float* __restrict__ proj_W,
    const float* __restrict__ proj_b, ushort* __restrict__ catp_bf)
{
    const int b = blockIdx.x;
    const int j = threadIdx.x;
    __shared__ float cat[768];

    float m[NCHK], lv[NCHK];
#pragma unroll
    for (int c = 0; c < NCHK; ++c) {
        m[c]  = mls[(b * NCHK + c) * 2 + 0];
        lv[c] = mls[(b * NCHK + c) * 2 + 1];
    }
    float ms = m[0];
#pragma unroll
    for (int c = 1; c < NCHK; ++c) ms = fmaxf(ms, m[c]);
    float wgt[NCHK], L = 0.f;
#pragma unroll
    for (int c = 0; c < NCHK; ++c) { wgt[c] = __expf(m[c] - ms); L += lv[c] * wgt[c]; }
    float inv = 1.0f / L;

#pragma unroll
    for (int p = 0; p < 2; ++p) {
        int f = j + p * 256;
        float s = 0.f;
#pragma unroll
        for (int c = 0; c < NCHK; ++c) s += ctxp[((size_t)(b * NCHK + c)) * F2H + f] * wgt[c];
        cat[f] = s * inv;
    }
    cat[F2H + j] = hvals[b * HID + j];
    __syncthreads();

    float acc = proj_b[j];
    const float* wr = proj_W + j * 768;
#pragma unroll 8
    for (int k = 0; k < 768; k += 4) {
        float4 wv = *(const float4*)&wr[k];
        acc += cat[k] * wv.x + cat[k + 1] * wv.y + cat[k + 2] * wv.z + cat[k + 3] * wv.w;
    }
    catp_bf[b * HID + j] = f2bf(acc);
}

// ---------------- K4: output GEMM — wave-contiguous out_W staging (L3-hot) ----------------
__global__ __launch_bounds__(512, 4) void k_out(
    const ushort* __restrict__ catp_bf, const float* __restrict__ out_W,
    const float* __restrict__ out_b, float* __restrict__ wd)
{
    __shared__ ushort Cs[64 * 256];
    __shared__ ushort Ws[64 * 256];

    const int tid = threadIdx.x;
    const int l = tid & 63;
    const int w = tid >> 6;
    const int q = l >> 4;
    const int ln = l & 15;
    const int wr = w >> 2, wc = w & 3;
    const int v0 = blockIdx.x * 64;

#pragma unroll
    for (int i = 0; i < 4; ++i) {
        int u = i * 512 + tid;
        int n = u >> 5, c16 = u & 31;
        bf16x8 o = *(const bf16x8*)&catp_bf[n * HID + c16 * 8];
        *(bf16x8*)&Cs[n * 256 + ((c16 ^ (n & 7)) * 8)] = o;
    }
#pragma unroll
    for (int i = 0; i < 4; ++i) {
        int idx = i * 512 + tid;
        int row = idx >> 5, g = idx & 31;
        int vr = v0 + row; if (vr >= VOC) vr = VOC - 1;
        const float4* src = (const float4*)&out_W[(size_t)vr * HID + g * 8];
        float4 f0 = src[0], f1 = src[1];
        *(bf16x8*)&Ws[row * 256 + ((g ^ (row & 7)) * 8)] = cvt8(f0, f1);
    }
    __syncthreads();

    f32x4 acc[2];
    acc[0] = (f32x4){0.f, 0.f, 0.f, 0.f};
    acc[1] = (f32x4){0.f, 0.f, 0.f, 0.f};

    const int vrow = wc * 16 + ln;
#pragma unroll
    for (int s = 0; s < 8; ++s) {
        int gB = (s * 4 + q) ^ (vrow & 7);
        bf16x8 bfr = *(const bf16x8*)&Ws[vrow * 256 + gB * 8];
#pragma unroll
        for (int mf = 0; mf < 2; ++mf) {
            int arow = wr * 32 + mf * 16 + ln;
            int gA = (s * 4 + q) ^ (arow & 7);
            bf16x8 a = *(const bf16x8*)&Cs[arow * 256 + gA * 8];
            acc[mf] = __builtin_amdgcn_mfma_f32_16x16x32_bf16(a, bfr, acc[mf], 0, 0, 0);
        }
    }

    const int v = v0 + vrow;
    if (v < VOC) {
        float bias = out_b[v];
#pragma unroll
        for (int mf = 0; mf < 2; ++mf) {
            int b0 = wr * 32 + mf * 16 + q * 4;
#pragma unroll
            for (int r = 0; r < 4; ++r)
                wd[(size_t)(b0 + r) * VOC + v] = acc[mf][r] + bias;
        }
    }
}

extern "C" void kernel_launch(void* const* d_in, const int* in_sizes, int n_in,
                              void* d_out, int out_size, void* d_ws, size_t ws_size,
                              hipStream_t stream) {
    const int*   word   = (const int*)  d_in[0];
    const float* hidden = (const float*)d_in[1];
    const float* cell   = (const float*)d_in[2];
    const float* enc    = (const float*)d_in[3];
    const float* embed  = (const float*)d_in[5];
    const float* W_ih   = (const float*)d_in[6];
    const float* W_hh   = (const float*)d_in[7];
    const float* b_ih   = (const float*)d_in[8];
    const float* b_hh   = (const float*)d_in[9];
    const float* attn_W = (const float*)d_in[10];
    const float* attn_b = (const float*)d_in[11];
    const float* vvec   = (const float*)d_in[12];
    const float* proj_W = (const float*)d_in[13];
    const float* proj_b = (const float*)d_in[14];
    const float* out_W  = (const float*)d_in[15];
    const float* out_b  = (const float*)d_in[16];

    float* wd  = (float*)d_out;
    float* h_o = wd + (size_t)BB * VOC;
    float* c_o = h_o + BB * HID;

    float* ws    = (float*)d_ws;
    float* part  = ws;                          // 262144
    float* hproj = part + 262144;               // 16384
    float* ctxp  = hproj + 16384;               // 229376
    float* mls   = ctxp + 229376;               // 896
    ushort* wenc_pk = (ushort*)(mls + 896);     // 131072 ushorts
    ushort* catp_bf = wenc_pk + 131072;         // 16384 ushorts
    float* pfdump = (float*)(catp_bf + 16384);  // 229376 floats

    k_gates<<<dim3(16, 5), 256, 0, stream>>>(word, hidden, embed, W_ih, W_hh, part, attn_W, wenc_pk);
    k_lstm<<<64, 256, 0, stream>>>(part, cell, b_ih, b_hh, attn_W, attn_b, h_o, c_o, hproj);
    k_attn<<<BB * NCHK, 512, 0, stream>>>(enc, wenc_pk, hproj, vvec, ctxp, mls, out_W, pfdump);
    k_comb<<<64, 256, 0, stream>>>(ctxp, mls, h_o, proj_W, proj_b, catp_bf);
    k_out<<<782, 512, 0, stream>>>(catp_bf, out_W, out_b, wd);
}

// Round 21
// 84.891 us; speedup vs baseline: 1.3816x; 1.0197x over previous
//
#include <hip/hip_runtime.h>
#include <hip/hip_bf16.h>
#include <math.h>

#define BB 64
#define SS 400
#define F2H 512
#define HID 256
#define EMB 128
#define NGATE 1024
#define VOC 50000
#define CH 64
#define NCHK 7
#define NKC 16

typedef short bf16x8 __attribute__((ext_vector_type(8)));
typedef float f32x4 __attribute__((ext_vector_type(4)));

__device__ __forceinline__ float sigm(float x) { return 1.0f / (1.0f + __expf(-x)); }

__device__ __forceinline__ float ftanh(float x) {
    float e = __expf(2.0f * x);
    return 1.0f - 2.0f / (e + 1.0f);
}

__device__ __forceinline__ ushort f2bf(float x) {
    uint32_t u = __float_as_uint(x);
    uint32_t r = u + 0x7FFFu + ((u >> 16) & 1u);
    return (ushort)(r >> 16);
}

__device__ __forceinline__ float bf2f(ushort u) {
    return __uint_as_float(((uint32_t)u) << 16);
}

__device__ __forceinline__ bf16x8 cvt8(float4 a, float4 b) {
    __hip_bfloat162 p0 = __float22bfloat162_rn({a.x, a.y});
    __hip_bfloat162 p1 = __float22bfloat162_rn({a.z, a.w});
    __hip_bfloat162 p2 = __float22bfloat162_rn({b.x, b.y});
    __hip_bfloat162 p3 = __float22bfloat162_rn({b.z, b.w});
    union { bf16x8 v; uint32_t u[4]; } r;
    r.u[0] = *(uint32_t*)&p0;
    r.u[1] = *(uint32_t*)&p1;
    r.u[2] = *(uint32_t*)&p2;
    r.u[3] = *(uint32_t*)&p3;
    return r.v;
}

// ---------------- K1a: gates partial GEMM + fused wenc MFMA-fragment packing ----------------
__global__ __launch_bounds__(256) void k_gates(
    const int* __restrict__ word, const float* __restrict__ hidden,
    const float* __restrict__ embed, const float* __restrict__ W_ih,
    const float* __restrict__ W_hh, float* __restrict__ part,
    const float* __restrict__ attn_W, ushort* __restrict__ wenc_pk)
{
    const int gt = blockIdx.x;
    const int ks = blockIdx.y;
    const int tid = threadIdx.x;

    if (ks == 4) {   // wenc fragment-packed prep
#pragma unroll
        for (int r = 0; r < 4; ++r) {
            int u = gt * 1024 + r * 256 + tid;
            int l = u & 63;
            int t = (u >> 6) & 15;
            int nt = u >> 10;
            int n = nt * 16 + (l & 15);
            int k0 = t * 32 + (l >> 4) * 8;
            const float4* src = (const float4*)&attn_W[n * 768 + k0];
            float4 f0 = src[0], f1 = src[1];
            *(bf16x8*)&wenc_pk[(size_t)u * 8] = cvt8(f0, f1);
        }
        return;
    }

    __shared__ float As[32 * 68];
    __shared__ float Bs[32 * 68];
    const int g0 = gt * 64;
    const int k0 = ks * 96;
    float acc[4][4];
#pragma unroll
    for (int i = 0; i < 4; ++i)
#pragma unroll
        for (int j = 0; j < 4; ++j) acc[i][j] = 0.0f;

    const int tb = tid >> 4;
    const int tg = tid & 15;
    const int srow = tid >> 3;
    const int skk = (tid & 7) * 4;

    for (int c = 0; c < 3; ++c) {
        const int kc = k0 + c * 32;
#pragma unroll
        for (int p = 0; p < 2; ++p) {
            int rr = srow + p * 32;
            int gk = kc + skk;
            float4 f;
            if (gk < EMB) {
                int w = word[rr];
                f = *(const float4*)&embed[w * EMB + gk];
            } else {
                f = *(const float4*)&hidden[rr * HID + gk - EMB];
            }
            As[(skk + 0) * 68 + rr] = f.x;
            As[(skk + 1) * 68 + rr] = f.y;
            As[(skk + 2) * 68 + rr] = f.z;
            As[(skk + 3) * 68 + rr] = f.w;
        }
#pragma unroll
        for (int p = 0; p < 2; ++p) {
            int nn = srow + p * 32;
            int g = g0 + nn;
            int gk = kc + skk;
            float4 f;
            if (gk < EMB) f = *(const float4*)&W_ih[g * EMB + gk];
            else          f = *(const float4*)&W_hh[g * HID + gk - EMB];
            Bs[(skk + 0) * 68 + nn] = f.x;
            Bs[(skk + 1) * 68 + nn] = f.y;
            Bs[(skk + 2) * 68 + nn] = f.z;
            Bs[(skk + 3) * 68 + nn] = f.w;
        }
        __syncthreads();
#pragma unroll 8
        for (int k = 0; k < 32; ++k) {
            float4 a = *(const float4*)&As[k * 68 + tb * 4];
            float4 b = *(const float4*)&Bs[k * 68 + tg * 4];
            float av[4] = {a.x, a.y, a.z, a.w};
            float bv[4] = {b.x, b.y, b.z, b.w};
#pragma unroll
            for (int i = 0; i < 4; ++i)
#pragma unroll
                for (int j = 0; j < 4; ++j) acc[i][j] += av[i] * bv[j];
        }
        __syncthreads();
    }
    float* dst = part + ks * (BB * NGATE);
#pragma unroll
    for (int i = 0; i < 4; ++i) {
        int b = tb * 4 + i;
        float4 o = {acc[i][0], acc[i][1], acc[i][2], acc[i][3]};
        *(float4*)&dst[b * NGATE + g0 + tg * 4] = o;
    }
}

// ---------------- K1b: LSTM pointwise + hproj ----------------
__global__ __launch_bounds__(256) void k_lstm(
    const float* __restrict__ part, const float* __restrict__ cell,
    const float* __restrict__ b_ih, const float* __restrict__ b_hh,
    const float* __restrict__ attn_W, const float* __restrict__ attn_b,
    float* __restrict__ h_out, float* __restrict__ c_out, float* __restrict__ hproj)
{
    const int b = blockIdx.x;
    const int u = threadIdx.x;
    __shared__ float hrow[HID];

    float gi = b_ih[u] + b_hh[u];
    float gf = b_ih[u + 256] + b_hh[u + 256];
    float gg = b_ih[u + 512] + b_hh[u + 512];
    float go = b_ih[u + 768] + b_hh[u + 768];
#pragma unroll
    for (int ks = 0; ks < 4; ++ks) {
        const float* p = part + ks * (BB * NGATE) + b * NGATE;
        gi += p[u];
        gf += p[u + 256];
        gg += p[u + 512];
        go += p[u + 768];
    }
    float c = sigm(gf) * cell[b * HID + u] + sigm(gi) * tanhf(gg);
    float h = tanhf(sigm(go) * tanhf(c));
    c_out[b * HID + u] = c;
    h_out[b * HID + u] = h;
    hrow[u] = h;
    __syncthreads();

    float acc = attn_b[u];
    const float* wr = attn_W + u * 768 + 512;
#pragma unroll 8
    for (int k = 0; k < HID; k += 4) {
        float4 w = *(const float4*)&wr[k];
        acc += hrow[k] * w.x + hrow[k + 1] * w.y + hrow[k + 2] * w.z + hrow[k + 3] * w.w;
    }
    hproj[b * HID + u] = acc;
}

// ---------------- K2: fused attention (no prefetch) ----------------
__global__ __launch_bounds__(512, 4) void k_attn(
    const float* __restrict__ enc, const ushort* __restrict__ wenc_pk,
    const float* __restrict__ hproj, const float* __restrict__ vvec,
    float* __restrict__ ctxp, float* __restrict__ mls)
{
    const int b   = blockIdx.x / NCHK;
    const int chk = blockIdx.x % NCHK;
    const int s0  = chk * CH;
    const int tid = threadIdx.x;
    const int l = tid & 63;
    const int w = tid >> 6;
    const int wr = w >> 2, wc = w & 3;
    const int brow0 = b * SS;
    const int ln = l & 15, q = l >> 4;

    __shared__ ushort Asm[CH * 512];
    __shared__ float ps[CH];
    __shared__ float pool[7 * 64 * 8];
    float (*epart)[4] = (float(*)[4])pool;
    float* scratch = pool;

#pragma unroll
    for (int i = 0; i < 8; ++i) {
        int u = i * 512 + tid;
        int row = u >> 6, c16 = u & 63;
        int sr = s0 + row;
        if (sr >= SS) sr = SS - 1;
        const float4* src = (const float4*)&enc[(size_t)(brow0 + sr) * F2H + c16 * 8];
        float4 f0 = src[0], f1 = src[1];
        *(bf16x8*)&Asm[row * 512 + ((c16 ^ (row & 7)) * 8)] = cvt8(f0, f1);
    }
    __syncthreads();

    f32x4 acc[2][4];
#pragma unroll
    for (int mf = 0; mf < 2; ++mf)
#pragma unroll
        for (int nf = 0; nf < 4; ++nf) acc[mf][nf] = (f32x4){0.f, 0.f, 0.f, 0.f};

    const ushort* bbase = wenc_pk + ((size_t)(wc * 4) * 1024 + l) * 8;

#pragma unroll
    for (int t = 0; t < NKC; ++t) {
        bf16x8 af[2], bfr[4];
#pragma unroll
        for (int nf = 0; nf < 4; ++nf)
            bfr[nf] = *(const bf16x8*)(bbase + ((size_t)nf * 1024 + t * 64) * 8);
#pragma unroll
        for (int mf = 0; mf < 2; ++mf) {
            int row = wr * 32 + mf * 16 + ln;
            int c16 = (t * 4 + q) ^ (row & 7);
            af[mf] = *(const bf16x8*)&Asm[row * 512 + c16 * 8];
        }
#pragma unroll
        for (int mf = 0; mf < 2; ++mf)
#pragma unroll
            for (int nf = 0; nf < 4; ++nf)
                acc[mf][nf] = __builtin_amdgcn_mfma_f32_16x16x32_bf16(
                    af[mf], bfr[nf], acc[mf][nf], 0, 0, 0);
    }

    float vv[4];
#pragma unroll
    for (int nf = 0; nf < 4; ++nf) vv[nf] = vvec[wc * 64 + nf * 16 + ln];
    const float* hp = hproj + b * HID;

#pragma unroll
    for (int mf = 0; mf < 2; ++mf) {
#pragma unroll
        for (int r = 0; r < 4; ++r) {
            int row = wr * 32 + mf * 16 + q * 4 + r;
            float p = 0.0f;
#pragma unroll
            for (int nf = 0; nf < 4; ++nf) {
                int col = wc * 64 + nf * 16 + ln;
                p += vv[nf] * ftanh(acc[mf][nf][r] + hp[col]);
            }
#pragma unroll
            for (int off = 8; off >= 1; off >>= 1) p += __shfl_xor(p, off);
            if (ln == 0) epart[row][wc] = p;
        }
    }
    __syncthreads();

    if (tid < 64) {
        int s = s0 + tid;
        float es = (s < SS)
            ? ((epart[tid][0] + epart[tid][1]) + (epart[tid][2] + epart[tid][3]))
            : -1e30f;
        float m = es;
#pragma unroll
        for (int off = 32; off >= 1; off >>= 1) m = fmaxf(m, __shfl_xor(m, off));
        float p = __expf(es - m);
        ps[tid] = p;
        float sum = p;
#pragma unroll
        for (int off = 32; off >= 1; off >>= 1) sum += __shfl_xor(sum, off);
        if (tid == 0) {
            mls[(b * NCHK + chk) * 2 + 0] = m;
            mls[(b * NCHK + chk) * 2 + 1] = sum;
        }
    }
    __syncthreads();

    {
        const int c16 = l;
        float ca[8];
#pragma unroll
        for (int j = 0; j < 8; ++j) ca[j] = 0.f;
#pragma unroll
        for (int r = 0; r < 8; ++r) {
            int row = w * 8 + r;
            float p = ps[row];
            bf16x8 v = *(const bf16x8*)&Asm[row * 512 + ((c16 ^ (row & 7)) * 8)];
#pragma unroll
            for (int j = 0; j < 8; ++j) ca[j] += p * bf2f((ushort)v[j]);
        }
        if (w != 0) {
#pragma unroll
            for (int j = 0; j < 8; ++j) scratch[((w - 1) * 64 + c16) * 8 + j] = ca[j];
        }
        __syncthreads();
        if (w == 0) {
#pragma unroll
            for (int g = 0; g < 7; ++g)
#pragma unroll
                for (int j = 0; j < 8; ++j) ca[j] += scratch[(g * 64 + c16) * 8 + j];
            float4 o0 = {ca[0], ca[1], ca[2], ca[3]};
            float4 o1 = {ca[4], ca[5], ca[6], ca[7]};
            float* dst = ctxp + (size_t)(b * NCHK + chk) * F2H + c16 * 8;
            *(float4*)dst = o0;
            *(float4*)(dst + 4) = o1;
        }
    }
}

// ---------------- K3: combine + projection -> MFMA-fragment-packed bf16 catp ----------------
// packed unit u = mtile*512 + t*64 + l, elem j = bf16(catp[mtile*16+(l&15)][t*32+(l>>4)*8+j])
__global__ __launch_bounds__(256) void k_comb(
    const float* __restrict__ ctxp, const float* __restrict__ mls,
    const float* __restrict__ hvals, const float* __restrict__ proj_W,
    const float* __restrict__ proj_b, ushort* __restrict__ catp_pk)
{
    const int b = blockIdx.x;
    const int j = threadIdx.x;
    __shared__ float cat[768];

    float m[NCHK], lv[NCHK];
#pragma unroll
    for (int c = 0; c < NCHK; ++c) {
        m[c]  = mls[(b * NCHK + c) * 2 + 0];
        lv[c] = mls[(b * NCHK + c) * 2 + 1];
    }
    float ms = m[0];
#pragma unroll
    for (int c = 1; c < NCHK; ++c) ms = fmaxf(ms, m[c]);
    float wgt[NCHK], L = 0.f;
#pragma unroll
    for (int c = 0; c < NCHK; ++c) { wgt[c] = __expf(m[c] - ms); L += lv[c] * wgt[c]; }
    float inv = 1.0f / L;

#pragma unroll
    for (int p = 0; p < 2; ++p) {
        int f = j + p * 256;
        float s = 0.f;
#pragma unroll
        for (int c = 0; c < NCHK; ++c) s += ctxp[((size_t)(b * NCHK + c)) * F2H + f] * wgt[c];
        cat[f] = s * inv;
    }
    cat[F2H + j] = hvals[b * HID + j];
    __syncthreads();

    float acc = proj_b[j];
    const float* wr = proj_W + j * 768;
#pragma unroll 8
    for (int k = 0; k < 768; k += 4) {
        float4 wv = *(const float4*)&wr[k];
        acc += cat[k] * wv.x + cat[k + 1] * wv.y + cat[k + 2] * wv.z + cat[k + 3] * wv.w;
    }
    // scatter into fragment-packed layout: col=j, row=b
    {
        int u = (b >> 4) * 512 + (j >> 5) * 64 + ((j >> 3) & 3) * 16 + (b & 15);
        catp_pk[u * 8 + (j & 7)] = f2bf(acc);
    }
}

// ---------------- K4: output GEMM — v-tile 32, A register-direct from packed catp, 4 blocks/CU ----------------
// grid 1563; 256 thr = 4 waves (wr=w>>1 m-half, wc=w&1 v-half of 16)
__global__ __launch_bounds__(256, 4) void k_out(
    const ushort* __restrict__ catp_pk, const float* __restrict__ out_W,
    const float* __restrict__ out_b, float* __restrict__ wd)
{
    __shared__ ushort Ws[32 * 256];   // out_W tile bf16, swizzled (16 KB)

    const int tid = threadIdx.x;
    const int l = tid & 63;
    const int w = tid >> 6;
    const int q = l >> 4;
    const int ln = l & 15;
    const int wr = w >> 1, wc = w & 1;
    const int v0 = blockIdx.x * 32;

    // stage out_W tile: 32 rows x 1 KB contiguous; 1024 units / 256 thr = 4 each
#pragma unroll
    for (int i = 0; i < 4; ++i) {
        int idx = i * 256 + tid;
        int row = idx >> 5, g = idx & 31;
        int vr = v0 + row; if (vr >= VOC) vr = VOC - 1;
        const float4* src = (const float4*)&out_W[(size_t)vr * HID + g * 8];
        float4 f0 = src[0], f1 = src[1];
        *(bf16x8*)&Ws[row * 256 + ((g ^ (row & 7)) * 8)] = cvt8(f0, f1);
    }
    __syncthreads();

    f32x4 acc[2];
    acc[0] = (f32x4){0.f, 0.f, 0.f, 0.f};
    acc[1] = (f32x4){0.f, 0.f, 0.f, 0.f};

    const int vrow = wc * 16 + ln;
    const ushort* abase = catp_pk + ((size_t)(wr * 2) * 512 + l) * 8;

#pragma unroll
    for (int t = 0; t < 8; ++t) {
        bf16x8 af[2];
        af[0] = *(const bf16x8*)(abase + ((size_t)0 * 512 + t * 64) * 8);
        af[1] = *(const bf16x8*)(abase + ((size_t)1 * 512 + t * 64) * 8);
        int gB = (t * 4 + q) ^ (vrow & 7);
        bf16x8 bfr = *(const bf16x8*)&Ws[vrow * 256 + gB * 8];
#pragma unroll
        for (int mf = 0; mf < 2; ++mf)
            acc[mf] = __builtin_amdgcn_mfma_f32_16x16x32_bf16(af[mf], bfr, acc[mf], 0, 0, 0);
    }

    const int v = v0 + vrow;
    if (v < VOC) {
        float bias = out_b[v];
#pragma unroll
        for (int mf = 0; mf < 2; ++mf) {
            int b0 = wr * 32 + mf * 16 + q * 4;
#pragma unroll
            for (int r = 0; r < 4; ++r)
                wd[(size_t)(b0 + r) * VOC + v] = acc[mf][r] + bias;
        }
    }
}

extern "C" void kernel_launch(void* const* d_in, const int* in_sizes, int n_in,
                              void* d_out, int out_size, void* d_ws, size_t ws_size,
                              hipStream_t stream) {
    const int*   word   = (const int*)  d_in[0];
    const float* hidden = (const float*)d_in[1];
    const float* cell   = (const float*)d_in[2];
    const float* enc    = (const float*)d_in[3];
    const float* embed  = (const float*)d_in[5];
    const float* W_ih   = (const float*)d_in[6];
    const float* W_hh   = (const float*)d_in[7];
    const float* b_ih   = (const float*)d_in[8];
    const float* b_hh   = (const float*)d_in[9];
    const float* attn_W = (const float*)d_in[10];
    const float* attn_b = (const float*)d_in[11];
    const float* vvec   = (const float*)d_in[12];
    const float* proj_W = (const float*)d_in[13];
    const float* proj_b = (const float*)d_in[14];
    const float* out_W  = (const float*)d_in[15];
    const float* out_b  = (const float*)d_in[16];

    float* wd  = (float*)d_out;
    float* h_o = wd + (size_t)BB * VOC;
    float* c_o = h_o + BB * HID;

    float* ws    = (float*)d_ws;
    float* part  = ws;                          // 262144
    float* hproj = part + 262144;               // 16384
    float* ctxp  = hproj + 16384;               // 229376
    float* mls   = ctxp + 229376;               // 896
    ushort* wenc_pk = (ushort*)(mls + 896);     // 131072 ushorts
    ushort* catp_pk = wenc_pk + 131072;         // 16384 ushorts

    k_gates<<<dim3(16, 5), 256, 0, stream>>>(word, hidden, embed, W_ih, W_hh, part, attn_W, wenc_pk);
    k_lstm<<<64, 256, 0, stream>>>(part, cell, b_ih, b_hh, attn_W, attn_b, h_o, c_o, hproj);
    k_attn<<<BB * NCHK, 512, 0, stream>>>(enc, wenc_pk, hproj, vvec, ctxp, mls);
    k_comb<<<64, 256, 0, stream>>>(ctxp, mls, h_o, proj_W, proj_b, catp_pk);
    k_out<<<1563, 256, 0, stream>>>(catp_pk, out_W, out_b, wd);
}

// Round 22
// 73.924 us; speedup vs baseline: 1.5865x; 1.1484x over previous
//
#include <hip/hip_runtime.h>
#include <hip/hip_bf16.h>
#include <math.h>

#define BB 64
#define SS 400
#define F2H 512
#define HID 256
#define EMB 128
#define NGATE 1024
#define VOC 50000
#define CH 64
#define NCHK 7
#define NKC 16
#define KSP 12

typedef short bf16x8 __attribute__((ext_vector_type(8)));
typedef float f32x4 __attribute__((ext_vector_type(4)));

__device__ __forceinline__ float sigm(float x) { return 1.0f / (1.0f + __expf(-x)); }

__device__ __forceinline__ float ftanh(float x) {
    float e = __expf(2.0f * x);
    return 1.0f - 2.0f / (e + 1.0f);
}

__device__ __forceinline__ ushort f2bf(float x) {
    uint32_t u = __float_as_uint(x);
    uint32_t r = u + 0x7FFFu + ((u >> 16) & 1u);
    return (ushort)(r >> 16);
}

__device__ __forceinline__ float bf2f(ushort u) {
    return __uint_as_float(((uint32_t)u) << 16);
}

__device__ __forceinline__ bf16x8 cvt8(float4 a, float4 b) {
    __hip_bfloat162 p0 = __float22bfloat162_rn({a.x, a.y});
    __hip_bfloat162 p1 = __float22bfloat162_rn({a.z, a.w});
    __hip_bfloat162 p2 = __float22bfloat162_rn({b.x, b.y});
    __hip_bfloat162 p3 = __float22bfloat162_rn({b.z, b.w});
    union { bf16x8 v; uint32_t u[4]; } r;
    r.u[0] = *(uint32_t*)&p0;
    r.u[1] = *(uint32_t*)&p1;
    r.u[2] = *(uint32_t*)&p2;
    r.u[3] = *(uint32_t*)&p3;
    return r.v;
}

// ---------------- K1a: gates partial GEMM (12-way k-split, 1 chunk/block) + wenc pack ----------------
// grid (16, 13): ks<12 -> gates k-chunk ks; ks==12 -> wenc pack (gt indexes)
__global__ __launch_bounds__(256) void k_gates(
    const int* __restrict__ word, const float* __restrict__ hidden,
    const float* __restrict__ embed, const float* __restrict__ W_ih,
    const float* __restrict__ W_hh, float* __restrict__ part,
    const float* __restrict__ attn_W, ushort* __restrict__ wenc_pk)
{
    const int gt = blockIdx.x;
    const int ks = blockIdx.y;
    const int tid = threadIdx.x;

    if (ks == KSP) {   // wenc fragment-packed prep
#pragma unroll
        for (int r = 0; r < 4; ++r) {
            int u = gt * 1024 + r * 256 + tid;
            int l = u & 63;
            int t = (u >> 6) & 15;
            int nt = u >> 10;
            int n = nt * 16 + (l & 15);
            int k0 = t * 32 + (l >> 4) * 8;
            const float4* src = (const float4*)&attn_W[n * 768 + k0];
            float4 f0 = src[0], f1 = src[1];
            *(bf16x8*)&wenc_pk[(size_t)u * 8] = cvt8(f0, f1);
        }
        return;
    }

    __shared__ float As[32 * 68];
    __shared__ float Bs[32 * 68];
    const int g0 = gt * 64;
    const int kc = ks * 32;
    float acc[4][4];
#pragma unroll
    for (int i = 0; i < 4; ++i)
#pragma unroll
        for (int j = 0; j < 4; ++j) acc[i][j] = 0.0f;

    const int tb = tid >> 4;
    const int tg = tid & 15;
    const int srow = tid >> 3;
    const int skk = (tid & 7) * 4;

    // stage A (64 x 32)
#pragma unroll
    for (int p = 0; p < 2; ++p) {
        int rr = srow + p * 32;
        int gk = kc + skk;
        float4 f;
        if (gk < EMB) {
            int w = word[rr];
            f = *(const float4*)&embed[w * EMB + gk];
        } else {
            f = *(const float4*)&hidden[rr * HID + gk - EMB];
        }
        As[(skk + 0) * 68 + rr] = f.x;
        As[(skk + 1) * 68 + rr] = f.y;
        As[(skk + 2) * 68 + rr] = f.z;
        As[(skk + 3) * 68 + rr] = f.w;
    }
    // stage B (64 x 32); chunk never straddles the W_ih/W_hh boundary (ks<4 -> W_ih)
#pragma unroll
    for (int p = 0; p < 2; ++p) {
        int nn = srow + p * 32;
        int g = g0 + nn;
        int gk = kc + skk;
        float4 f;
        if (gk < EMB) f = *(const float4*)&W_ih[g * EMB + gk];
        else          f = *(const float4*)&W_hh[g * HID + gk - EMB];
        Bs[(skk + 0) * 68 + nn] = f.x;
        Bs[(skk + 1) * 68 + nn] = f.y;
        Bs[(skk + 2) * 68 + nn] = f.z;
        Bs[(skk + 3) * 68 + nn] = f.w;
    }
    __syncthreads();
#pragma unroll 8
    for (int k = 0; k < 32; ++k) {
        float4 a = *(const float4*)&As[k * 68 + tb * 4];
        float4 b = *(const float4*)&Bs[k * 68 + tg * 4];
        float av[4] = {a.x, a.y, a.z, a.w};
        float bv[4] = {b.x, b.y, b.z, b.w};
#pragma unroll
        for (int i = 0; i < 4; ++i)
#pragma unroll
            for (int j = 0; j < 4; ++j) acc[i][j] += av[i] * bv[j];
    }
    float* dst = part + ks * (BB * NGATE);
#pragma unroll
    for (int i = 0; i < 4; ++i) {
        int b = tb * 4 + i;
        float4 o = {acc[i][0], acc[i][1], acc[i][2], acc[i][3]};
        *(float4*)&dst[b * NGATE + g0 + tg * 4] = o;
    }
}

// ---------------- K1b: LSTM pointwise + hproj (4-way col-split, 256 blocks) ----------------
// grid (64 b, 4 col-groups); 256 thr
__global__ __launch_bounds__(256) void k_lstm(
    const float* __restrict__ part, const float* __restrict__ cell,
    const float* __restrict__ b_ih, const float* __restrict__ b_hh,
    const float* __restrict__ attn_W, const float* __restrict__ attn_b,
    float* __restrict__ h_out, float* __restrict__ c_out, float* __restrict__ hproj)
{
    const int b = blockIdx.x;
    const int qg = blockIdx.y;
    const int u = threadIdx.x;
    __shared__ float hrow[HID];

    float gi = b_ih[u] + b_hh[u];
    float gf = b_ih[u + 256] + b_hh[u + 256];
    float gg = b_ih[u + 512] + b_hh[u + 512];
    float go = b_ih[u + 768] + b_hh[u + 768];
#pragma unroll
    for (int ks = 0; ks < KSP; ++ks) {
        const float* p = part + ks * (BB * NGATE) + b * NGATE;
        gi += p[u];
        gf += p[u + 256];
        gg += p[u + 512];
        go += p[u + 768];
    }
    float c = sigm(gf) * cell[b * HID + u] + sigm(gi) * tanhf(gg);
    float h = tanhf(sigm(go) * tanhf(c));
    if (qg == 0) {
        c_out[b * HID + u] = c;
        h_out[b * HID + u] = h;
    }
    hrow[u] = h;
    __syncthreads();

    // hproj for cols qg*64..+63: 4 threads per col, each 64 k's, 4-lane shuffle reduce
    const int col = qg * 64 + (u >> 2);
    const int kq = u & 3;
    const float* wr = attn_W + col * 768 + 512 + kq * 64;
    const float* hr = hrow + kq * 64;
    float acc = 0.f;
#pragma unroll 8
    for (int k = 0; k < 64; k += 4) {
        float4 wv = *(const float4*)&wr[k];
        acc += hr[k] * wv.x + hr[k + 1] * wv.y + hr[k + 2] * wv.z + hr[k + 3] * wv.w;
    }
    acc += __shfl_xor(acc, 1);
    acc += __shfl_xor(acc, 2);
    if (kq == 0) hproj[b * HID + col] = acc + attn_b[col];
}

// ---------------- K2: fused attention ----------------
__global__ __launch_bounds__(512, 4) void k_attn(
    const float* __restrict__ enc, const ushort* __restrict__ wenc_pk,
    const float* __restrict__ hproj, const float* __restrict__ vvec,
    float* __restrict__ ctxp, float* __restrict__ mls)
{
    const int b   = blockIdx.x / NCHK;
    const int chk = blockIdx.x % NCHK;
    const int s0  = chk * CH;
    const int tid = threadIdx.x;
    const int l = tid & 63;
    const int w = tid >> 6;
    const int wr = w >> 2, wc = w & 3;
    const int brow0 = b * SS;
    const int ln = l & 15, q = l >> 4;

    __shared__ ushort Asm[CH * 512];
    __shared__ float ps[CH];
    __shared__ float pool[7 * 64 * 8];
    float (*epart)[4] = (float(*)[4])pool;
    float* scratch = pool;

#pragma unroll
    for (int i = 0; i < 8; ++i) {
        int u = i * 512 + tid;
        int row = u >> 6, c16 = u & 63;
        int sr = s0 + row;
        if (sr >= SS) sr = SS - 1;
        const float4* src = (const float4*)&enc[(size_t)(brow0 + sr) * F2H + c16 * 8];
        float4 f0 = src[0], f1 = src[1];
        *(bf16x8*)&Asm[row * 512 + ((c16 ^ (row & 7)) * 8)] = cvt8(f0, f1);
    }
    __syncthreads();

    f32x4 acc[2][4];
#pragma unroll
    for (int mf = 0; mf < 2; ++mf)
#pragma unroll
        for (int nf = 0; nf < 4; ++nf) acc[mf][nf] = (f32x4){0.f, 0.f, 0.f, 0.f};

    const ushort* bbase = wenc_pk + ((size_t)(wc * 4) * 1024 + l) * 8;

#pragma unroll
    for (int t = 0; t < NKC; ++t) {
        bf16x8 af[2], bfr[4];
#pragma unroll
        for (int nf = 0; nf < 4; ++nf)
            bfr[nf] = *(const bf16x8*)(bbase + ((size_t)nf * 1024 + t * 64) * 8);
#pragma unroll
        for (int mf = 0; mf < 2; ++mf) {
            int row = wr * 32 + mf * 16 + ln;
            int c16 = (t * 4 + q) ^ (row & 7);
            af[mf] = *(const bf16x8*)&Asm[row * 512 + c16 * 8];
        }
#pragma unroll
        for (int mf = 0; mf < 2; ++mf)
#pragma unroll
            for (int nf = 0; nf < 4; ++nf)
                acc[mf][nf] = __builtin_amdgcn_mfma_f32_16x16x32_bf16(
                    af[mf], bfr[nf], acc[mf][nf], 0, 0, 0);
    }

    float vv[4];
#pragma unroll
    for (int nf = 0; nf < 4; ++nf) vv[nf] = vvec[wc * 64 + nf * 16 + ln];
    const float* hp = hproj + b * HID;

#pragma unroll
    for (int mf = 0; mf < 2; ++mf) {
#pragma unroll
        for (int r = 0; r < 4; ++r) {
            int row = wr * 32 + mf * 16 + q * 4 + r;
            float p = 0.0f;
#pragma unroll
            for (int nf = 0; nf < 4; ++nf) {
                int col = wc * 64 + nf * 16 + ln;
                p += vv[nf] * ftanh(acc[mf][nf][r] + hp[col]);
            }
#pragma unroll
            for (int off = 8; off >= 1; off >>= 1) p += __shfl_xor(p, off);
            if (ln == 0) epart[row][wc] = p;
        }
    }
    __syncthreads();

    if (tid < 64) {
        int s = s0 + tid;
        float es = (s < SS)
            ? ((epart[tid][0] + epart[tid][1]) + (epart[tid][2] + epart[tid][3]))
            : -1e30f;
        float m = es;
#pragma unroll
        for (int off = 32; off >= 1; off >>= 1) m = fmaxf(m, __shfl_xor(m, off));
        float p = __expf(es - m);
        ps[tid] = p;
        float sum = p;
#pragma unroll
        for (int off = 32; off >= 1; off >>= 1) sum += __shfl_xor(sum, off);
        if (tid == 0) {
            mls[(b * NCHK + chk) * 2 + 0] = m;
            mls[(b * NCHK + chk) * 2 + 1] = sum;
        }
    }
    __syncthreads();

    {
        const int c16 = l;
        float ca[8];
#pragma unroll
        for (int j = 0; j < 8; ++j) ca[j] = 0.f;
#pragma unroll
        for (int r = 0; r < 8; ++r) {
            int row = w * 8 + r;
            float p = ps[row];
            bf16x8 v = *(const bf16x8*)&Asm[row * 512 + ((c16 ^ (row & 7)) * 8)];
#pragma unroll
            for (int j = 0; j < 8; ++j) ca[j] += p * bf2f((ushort)v[j]);
        }
        if (w != 0) {
#pragma unroll
            for (int j = 0; j < 8; ++j) scratch[((w - 1) * 64 + c16) * 8 + j] = ca[j];
        }
        __syncthreads();
        if (w == 0) {
#pragma unroll
            for (int g = 0; g < 7; ++g)
#pragma unroll
                for (int j = 0; j < 8; ++j) ca[j] += scratch[(g * 64 + c16) * 8 + j];
            float4 o0 = {ca[0], ca[1], ca[2], ca[3]};
            float4 o1 = {ca[4], ca[5], ca[6], ca[7]};
            float* dst = ctxp + (size_t)(b * NCHK + chk) * F2H + c16 * 8;
            *(float4*)dst = o0;
            *(float4*)(dst + 4) = o1;
        }
    }
}

// ---------------- K3: combine + projection -> MFMA-fragment-packed bf16 catp ----------------
__global__ __launch_bounds__(256) void k_comb(
    const float* __restrict__ ctxp, const float* __restrict__ mls,
    const float* __restrict__ hvals, const float* __restrict__ proj_W,
    const float* __restrict__ proj_b, ushort* __restrict__ catp_pk)
{
    const int b = blockIdx.x;
    const int j = threadIdx.x;
    __shared__ float cat[768];

    float m[NCHK], lv[NCHK];
#pragma unroll
    for (int c = 0; c < NCHK; ++c) {
        m[c]  = mls[(b * NCHK + c) * 2 + 0];
        lv[c] = mls[(b * NCHK + c) * 2 + 1];
    }
    float ms = m[0];
#pragma unroll
    for (int c = 1; c < NCHK; ++c) ms = fmaxf(ms, m[c]);
    float wgt[NCHK], L = 0.f;
#pragma unroll
    for (int c = 0; c < NCHK; ++c) { wgt[c] = __expf(m[c] - ms); L += lv[c] * wgt[c]; }
    float inv = 1.0f / L;

#pragma unroll
    for (int p = 0; p < 2; ++p) {
        int f = j + p * 256;
        float s = 0.f;
#pragma unroll
        for (int c = 0; c < NCHK; ++c) s += ctxp[((size_t)(b * NCHK + c)) * F2H + f] * wgt[c];
        cat[f] = s * inv;
    }
    cat[F2H + j] = hvals[b * HID + j];
    __syncthreads();

    float acc = proj_b[j];
    const float* wr = proj_W + j * 768;
#pragma unroll 8
    for (int k = 0; k < 768; k += 4) {
        float4 wv = *(const float4*)&wr[k];
        acc += cat[k] * wv.x + cat[k + 1] * wv.y + cat[k + 2] * wv.z + cat[k + 3] * wv.w;
    }
    {
        int u = (b >> 4) * 512 + (j >> 5) * 64 + ((j >> 3) & 3) * 16 + (b & 15);
        catp_pk[u * 8 + (j & 7)] = f2bf(acc);
    }
}

// ---------------- K4: output GEMM — v-tile 32, A register-direct, 4 blocks/CU ----------------
__global__ __launch_bounds__(256, 4) void k_out(
    const ushort* __restrict__ catp_pk, const float* __restrict__ out_W,
    const float* __restrict__ out_b, float* __restrict__ wd)
{
    __shared__ ushort Ws[32 * 256];

    const int tid = threadIdx.x;
    const int l = tid & 63;
    const int w = tid >> 6;
    const int q = l >> 4;
    const int ln = l & 15;
    const int wr = w >> 1, wc = w & 1;
    const int v0 = blockIdx.x * 32;

#pragma unroll
    for (int i = 0; i < 4; ++i) {
        int idx = i * 256 + tid;
        int row = idx >> 5, g = idx & 31;
        int vr = v0 + row; if (vr >= VOC) vr = VOC - 1;
        const float4* src = (const float4*)&out_W[(size_t)vr * HID + g * 8];
        float4 f0 = src[0], f1 = src[1];
        *(bf16x8*)&Ws[row * 256 + ((g ^ (row & 7)) * 8)] = cvt8(f0, f1);
    }
    __syncthreads();

    f32x4 acc[2];
    acc[0] = (f32x4){0.f, 0.f, 0.f, 0.f};
    acc[1] = (f32x4){0.f, 0.f, 0.f, 0.f};

    const int vrow = wc * 16 + ln;
    const ushort* abase = catp_pk + ((size_t)(wr * 2) * 512 + l) * 8;

#pragma unroll
    for (int t = 0; t < 8; ++t) {
        bf16x8 af[2];
        af[0] = *(const bf16x8*)(abase + ((size_t)0 * 512 + t * 64) * 8);
        af[1] = *(const bf16x8*)(abase + ((size_t)1 * 512 + t * 64) * 8);
        int gB = (t * 4 + q) ^ (vrow & 7);
        bf16x8 bfr = *(const bf16x8*)&Ws[vrow * 256 + gB * 8];
#pragma unroll
        for (int mf = 0; mf < 2; ++mf)
            acc[mf] = __builtin_amdgcn_mfma_f32_16x16x32_bf16(af[mf], bfr, acc[mf], 0, 0, 0);
    }

    const int v = v0 + vrow;
    if (v < VOC) {
        float bias = out_b[v];
#pragma unroll
        for (int mf = 0; mf < 2; ++mf) {
            int b0 = wr * 32 + mf * 16 + q * 4;
#pragma unroll
            for (int r = 0; r < 4; ++r)
                wd[(size_t)(b0 + r) * VOC + v] = acc[mf][r] + bias;
        }
    }
}

extern "C" void kernel_launch(void* const* d_in, const int* in_sizes, int n_in,
                              void* d_out, int out_size, void* d_ws, size_t ws_size,
                              hipStream_t stream) {
    const int*   word   = (const int*)  d_in[0];
    const float* hidden = (const float*)d_in[1];
    const float* cell   = (const float*)d_in[2];
    const float* enc    = (const float*)d_in[3];
    const float* embed  = (const float*)d_in[5];
    const float* W_ih   = (const float*)d_in[6];
    const float* W_hh   = (const float*)d_in[7];
    const float* b_ih   = (const float*)d_in[8];
    const float* b_hh   = (const float*)d_in[9];
    const float* attn_W = (const float*)d_in[10];
    const float* attn_b = (const float*)d_in[11];
    const float* vvec   = (const float*)d_in[12];
    const float* proj_W = (const float*)d_in[13];
    const float* proj_b = (const float*)d_in[14];
    const float* out_W  = (const float*)d_in[15];
    const float* out_b  = (const float*)d_in[16];

    float* wd  = (float*)d_out;
    float* h_o = wd + (size_t)BB * VOC;
    float* c_o = h_o + BB * HID;

    float* ws    = (float*)d_ws;
    float* part  = ws;                          // 12*64*1024 = 786432
    float* hproj = part + 786432;               // 16384
    float* ctxp  = hproj + 16384;               // 229376
    float* mls   = ctxp + 229376;               // 896
    ushort* wenc_pk = (ushort*)(mls + 896);     // 131072 ushorts
    ushort* catp_pk = wenc_pk + 131072;         // 16384 ushorts

    k_gates<<<dim3(16, KSP + 1), 256, 0, stream>>>(word, hidden, embed, W_ih, W_hh, part, attn_W, wenc_pk);
    k_lstm<<<dim3(64, 4), 256, 0, stream>>>(part, cell, b_ih, b_hh, attn_W, attn_b, h_o, c_o, hproj);
    k_attn<<<BB * NCHK, 512, 0, stream>>>(enc, wenc_pk, hproj, vvec, ctxp, mls);
    k_comb<<<64, 256, 0, stream>>>(ctxp, mls, h_o, proj_W, proj_b, catp_pk);
    k_out<<<1563, 256, 0, stream>>>(catp_pk, out_W, out_b, wd);
}